// Round 8
// baseline (25.942 us; speedup 1.0000x reference)
//
#include <hip/hip_runtime.h>
#include <math.h>

// Problem geometry (fixed by reference setup_inputs)
#define B_ 32
#define S_ 512
#define D_ 1024
#define EPS_ 1e-8f
#define BETA_ 0.1
#define NCH 64           // S-chunks per batch (grid = B*NCH = 2048 blocks)
#define TCH (S_ / NCH)   // 8 timesteps per chunk

// ---------- helpers ----------

// mask layout flag: 0 = int32 (0/1), 1 = byte bool, 2 = float32 (0/1.0)
__device__ __forceinline__ float mask_val(const void* mp, int lay, int idx) {
  if (lay == 1) return ((const unsigned char*)mp)[idx] ? 1.0f : 0.0f;
  if (lay == 2) return (((const float*)mp)[idx] != 0.0f) ? 1.0f : 0.0f;
  return ((const int*)mp)[idx] ? 1.0f : 0.0f;
}

__device__ __forceinline__ float wave_sum_f(float v) {
#pragma unroll
  for (int off = 32; off > 0; off >>= 1) v += __shfl_down(v, off);
  return v;
}
__device__ __forceinline__ double wave_sum_d(double v) {
#pragma unroll
  for (int off = 32; off > 0; off >>= 1) v += __shfl_down(v, off);
  return v;
}

// In-block mask-layout detection from the first 1 KB of the mask buffer
// (uniform result across blocks; L2-hot).
__device__ __forceinline__ int detect_layout(const void* mask, int tid,
                                             int* sflags) {
  if (tid == 0) *sflags = 0;
  __syncthreads();
  unsigned int wv = ((const unsigned int*)mask)[tid & 255];
  int f = 0;
  if (wv == 0x3F800000u) f = 2;
  else if (wv > 1u) f = 1;
  if (f) atomicOr(sflags, f);
  __syncthreads();
  const int fl = *sflags;
  return (fl & 1) ? 1 : ((fl & 2) ? 2 : 0);
}

// ---------- kernel 1 (fused): single pass over fix_outputs ----------
// r2-proven inner structure; ONLY change: NCH 32->64 (8 blocks/CU, 32
// waves/CU = max occupancy) to double outstanding HBM load streams.
__global__ __launch_bounds__(256, 8) void fused_kernel(
    const float* __restrict__ fix, const void* __restrict__ mask,
    float* __restrict__ part, float* __restrict__ diagpart) {
  const int blk = blockIdx.x;
  const int b = blk >> 6;        // / NCH
  const int ch = blk & 63;       // % NCH
  const int tid = threadIdx.x;

  __shared__ int sflags;
  const int lay = detect_layout(mask, tid, &sflags);

  // this thread's mask for its 4 feature dims (constant over t)
  const int mb = b * D_ + tid * 4;
  float4 m4;
  m4.x = mask_val(mask, lay, mb + 0);
  m4.y = mask_val(mask, lay, mb + 1);
  m4.z = mask_val(mask, lay, mb + 2);
  m4.w = mask_val(mask, lay, mb + 3);

  const float4* base =
      (const float4*)(fix + ((size_t)b * S_ + (size_t)ch * TCH) * D_);

  __shared__ float red[4];
  float4 acc = make_float4(0.0f, 0.0f, 0.0f, 0.0f);
  float diag = 0.0f;

  float4 v = base[tid];  // prefetch row 0
  for (int t = 0; t < TCH; ++t) {
    float4 vn = make_float4(0.0f, 0.0f, 0.0f, 0.0f);
    if (t + 1 < TCH) vn = base[(size_t)(t + 1) * (D_ / 4) + tid];  // prefetch

    float ssq = v.x * v.x * m4.x + v.y * v.y * m4.y +
                v.z * v.z * m4.z + v.w * v.w * m4.w;
    ssq = wave_sum_f(ssq);
    if ((tid & 63) == 0) red[tid >> 6] = ssq;
    __syncthreads();
    const float s = red[0] + red[1] + red[2] + red[3];
    const float inv = 1.0f / fmaxf(sqrtf(fmaxf(s, 0.0f)), EPS_);
    acc.x += v.x * inv; acc.y += v.y * inv;
    acc.z += v.z * inv; acc.w += v.w * inv;
    diag += s * inv * inv;  // sim[t,t] (1.0 normally, 0 if fully masked row)
    v = vn;
    __syncthreads();  // protect red[] reuse next iteration
  }

  // unmasked column partials (mask applied once in reduce; m binary, t-indep)
  ((float4*)(part + (size_t)ch * (B_ * D_) + (size_t)b * D_))[tid] = acc;
  if (tid == 0) diagpart[blk] = diag;
}

// ---------- kernel 2: deterministic reduction to 128 block partials ----------
__global__ __launch_bounds__(256) void reduce_kernel(
    const float* __restrict__ part, const void* __restrict__ mask,
    const float* __restrict__ diagpart, double* __restrict__ blkout) {
  const int tid = threadIdx.x;
  const int gid = blockIdx.x * 256 + tid;  // 0 .. B*D-1 (32767)

  __shared__ int sflags;
  const int lay = detect_layout(mask, tid, &sflags);

  float s = 0.0f;
#pragma unroll
  for (int c = 0; c < NCH; ++c) s += part[c * (B_ * D_) + gid];
  const float sm = s * mask_val(mask, lay, gid);
  double full = (double)sm * (double)sm;
  full = wave_sum_d(full);
  __shared__ double redf[4];
  if ((tid & 63) == 0) redf[tid >> 6] = full;
  __syncthreads();
  if (tid == 0) {
    // each block also owns 16 of the 2048 diag partials (fixed order)
    double dg = 0.0;
#pragma unroll
    for (int k = 0; k < 16; ++k) dg += (double)diagpart[blockIdx.x * 16 + k];
    blkout[blockIdx.x * 2 + 0] = (redf[0] + redf[1]) + (redf[2] + redf[3]);
    blkout[blockIdx.x * 2 + 1] = dg;
  }
}

// ---------- kernel 3: final scalar ----------
__global__ __launch_bounds__(128) void final_kernel(
    const double* __restrict__ blkout, float* __restrict__ out) {
  const int tid = threadIdx.x;  // 128 threads <- 128 block partials
  double f = blkout[tid * 2 + 0];
  double g = blkout[tid * 2 + 1];
  f = wave_sum_d(f);
  g = wave_sum_d(g);
  __shared__ double rf[2], rg[2];
  if ((tid & 63) == 0) { rf[tid >> 6] = f; rg[tid >> 6] = g; }
  __syncthreads();
  if (tid == 0) {
    const double F = rf[0] + rf[1];   // sum_b sum_d m * (sum_t x/n)^2
    const double G = rg[0] + rg[1];   // sum of diagonal sims
    const double total = 0.5 * (F - G);                     // strict upper tri
    const double count = (double)B_ * S_ * (S_ - 1) / 2.0;  // 4,186,112
    const double avg = total / count;
    const double val = -log(1.0 - 0.5 * (avg + 1.0)) * BETA_;
    out[0] = (float)val;
  }
}

extern "C" void kernel_launch(void* const* d_in, const int* in_sizes, int n_in,
                              void* d_out, int out_size, void* d_ws, size_t ws_size,
                              hipStream_t stream) {
  const float* fix = (const float*)d_in[0];
  const void* mask = d_in[1];
  char* ws = (char*)d_ws;

  // workspace layout (256B-aligned)
  const size_t part_bytes = (size_t)NCH * B_ * D_ * sizeof(float);  // 8 MiB
  float* part     = (float*)ws;
  float* diagpart = (float*)(ws + part_bytes);                      // 2048 f32
  double* blkout  = (double*)(ws + part_bytes + 16384);             // 256 f64

  float* out = (float*)d_out;

  fused_kernel<<<B_ * NCH, 256, 0, stream>>>(fix, mask, part, diagpart);
  reduce_kernel<<<(B_ * D_) / 256, 256, 0, stream>>>(part, mask, diagpart, blkout);
  final_kernel<<<1, 128, 0, stream>>>(blkout, out);
}

// Round 9
// 23.038 us; speedup vs baseline: 1.1260x; 1.1260x over previous
//
#include <hip/hip_runtime.h>
#include <math.h>

// Problem geometry (fixed by reference setup_inputs)
#define B_ 32
#define S_ 512
#define D_ 1024
#define EPS_ 1e-8f
#define BETA_ 0.1
#define NCH 32           // S-chunks per batch (grid = B*NCH = 1024 blocks)
#define TCH (S_ / NCH)   // 16 timesteps per chunk

// ---------- helpers ----------

// mask layout flag: 0 = int32 (0/1), 1 = byte bool, 2 = float32 (0/1.0)
__device__ __forceinline__ float mask_val(const void* mp, int lay, int idx) {
  if (lay == 1) return ((const unsigned char*)mp)[idx] ? 1.0f : 0.0f;
  if (lay == 2) return (((const float*)mp)[idx] != 0.0f) ? 1.0f : 0.0f;
  return ((const int*)mp)[idx] ? 1.0f : 0.0f;
}

__device__ __forceinline__ float wave_sum_f(float v) {
#pragma unroll
  for (int off = 32; off > 0; off >>= 1) v += __shfl_down(v, off);
  return v;
}
__device__ __forceinline__ double wave_sum_d(double v) {
#pragma unroll
  for (int off = 32; off > 0; off >>= 1) v += __shfl_down(v, off);
  return v;
}

// In-block mask-layout detection from the first 1 KB of the mask buffer
// (uniform result across blocks; L2-hot).
__device__ __forceinline__ int detect_layout(const void* mask, int tid,
                                             int* sflags) {
  if (tid == 0) *sflags = 0;
  __syncthreads();
  unsigned int wv = ((const unsigned int*)mask)[tid & 255];
  int f = 0;
  if (wv == 0x3F800000u) f = 2;       // float 1.0 pattern
  else if (wv > 1u) f = 1;            // packed byte-bool pattern
  if (f) atomicOr(sflags, f);
  __syncthreads();
  const int fl = *sflags;
  return (fl & 1) ? 1 : ((fl & 2) ? 2 : 0);
}

// ---------- kernel 1 (fused): single pass over fix_outputs ----------
// Best-measured structure (r2, 22.9 us total). One block per (b, S-chunk);
// thread owns 4 consecutive dims (float4). Per row t: block-reduce masked
// ssq -> inv_n -> weight row into register column accumulator. Input is
// read exactly once.
__global__ __launch_bounds__(256) void fused_kernel(
    const float* __restrict__ fix, const void* __restrict__ mask,
    float* __restrict__ part, float* __restrict__ diagpart) {
  const int blk = blockIdx.x;
  const int b = blk >> 5;        // / NCH
  const int ch = blk & 31;       // % NCH
  const int tid = threadIdx.x;

  __shared__ int sflags;
  const int lay = detect_layout(mask, tid, &sflags);

  // this thread's mask for its 4 feature dims (constant over t)
  const int mb = b * D_ + tid * 4;
  float4 m4;
  m4.x = mask_val(mask, lay, mb + 0);
  m4.y = mask_val(mask, lay, mb + 1);
  m4.z = mask_val(mask, lay, mb + 2);
  m4.w = mask_val(mask, lay, mb + 3);

  const float4* base =
      (const float4*)(fix + ((size_t)b * S_ + (size_t)ch * TCH) * D_);

  __shared__ float red[4];
  float4 acc = make_float4(0.0f, 0.0f, 0.0f, 0.0f);
  float diag = 0.0f;

  float4 v = base[tid];  // prefetch row 0
  for (int t = 0; t < TCH; ++t) {
    float4 vn = make_float4(0.0f, 0.0f, 0.0f, 0.0f);
    if (t + 1 < TCH) vn = base[(size_t)(t + 1) * (D_ / 4) + tid];  // prefetch

    float ssq = v.x * v.x * m4.x + v.y * v.y * m4.y +
                v.z * v.z * m4.z + v.w * v.w * m4.w;
    ssq = wave_sum_f(ssq);
    if ((tid & 63) == 0) red[tid >> 6] = ssq;
    __syncthreads();
    const float s = red[0] + red[1] + red[2] + red[3];
    const float inv = 1.0f / fmaxf(sqrtf(fmaxf(s, 0.0f)), EPS_);
    acc.x += v.x * inv; acc.y += v.y * inv;
    acc.z += v.z * inv; acc.w += v.w * inv;
    diag += s * inv * inv;  // sim[t,t] (1.0 normally, 0 if fully masked row)
    v = vn;
    __syncthreads();  // protect red[] reuse next iteration
  }

  // unmasked column partials (mask applied once in reduce; m binary, t-indep)
  ((float4*)(part + (size_t)ch * (B_ * D_) + (size_t)b * D_))[tid] = acc;
  if (tid == 0) diagpart[blk] = diag;
}

// ---------- kernel 2: deterministic reduction to 128 block partials ----------
__global__ __launch_bounds__(256) void reduce_kernel(
    const float* __restrict__ part, const void* __restrict__ mask,
    const float* __restrict__ diagpart, double* __restrict__ blkout) {
  const int tid = threadIdx.x;
  const int gid = blockIdx.x * 256 + tid;  // 0 .. B*D-1 (32767)

  __shared__ int sflags;
  const int lay = detect_layout(mask, tid, &sflags);

  float s = 0.0f;
#pragma unroll
  for (int c = 0; c < NCH; ++c) s += part[c * (B_ * D_) + gid];
  const float sm = s * mask_val(mask, lay, gid);
  double full = (double)sm * (double)sm;
  full = wave_sum_d(full);
  __shared__ double redf[4];
  if ((tid & 63) == 0) redf[tid >> 6] = full;
  __syncthreads();
  if (tid == 0) {
    // each block also owns 8 of the 1024 diag partials (fixed order)
    double dg = 0.0;
#pragma unroll
    for (int k = 0; k < 8; ++k) dg += (double)diagpart[blockIdx.x * 8 + k];
    blkout[blockIdx.x * 2 + 0] = (redf[0] + redf[1]) + (redf[2] + redf[3]);
    blkout[blockIdx.x * 2 + 1] = dg;
  }
}

// ---------- kernel 3: final scalar ----------
__global__ __launch_bounds__(128) void final_kernel(
    const double* __restrict__ blkout, float* __restrict__ out) {
  const int tid = threadIdx.x;  // 128 threads <- 128 block partials
  double f = blkout[tid * 2 + 0];
  double g = blkout[tid * 2 + 1];
  f = wave_sum_d(f);
  g = wave_sum_d(g);
  __shared__ double rf[2], rg[2];
  if ((tid & 63) == 0) { rf[tid >> 6] = f; rg[tid >> 6] = g; }
  __syncthreads();
  if (tid == 0) {
    const double F = rf[0] + rf[1];   // sum_b sum_d m * (sum_t x/n)^2
    const double G = rg[0] + rg[1];   // sum of diagonal sims
    const double total = 0.5 * (F - G);                     // strict upper tri
    const double count = (double)B_ * S_ * (S_ - 1) / 2.0;  // 4,186,112
    const double avg = total / count;
    const double val = -log(1.0 - 0.5 * (avg + 1.0)) * BETA_;
    out[0] = (float)val;
  }
}

extern "C" void kernel_launch(void* const* d_in, const int* in_sizes, int n_in,
                              void* d_out, int out_size, void* d_ws, size_t ws_size,
                              hipStream_t stream) {
  const float* fix = (const float*)d_in[0];
  const void* mask = d_in[1];
  char* ws = (char*)d_ws;

  // workspace layout (256B-aligned)
  const size_t part_bytes = (size_t)NCH * B_ * D_ * sizeof(float);  // 4 MiB
  float* part     = (float*)ws;
  float* diagpart = (float*)(ws + part_bytes);                      // 1024 f32
  double* blkout  = (double*)(ws + part_bytes + 8192);              // 256 f64

  float* out = (float*)d_out;

  fused_kernel<<<B_ * NCH, 256, 0, stream>>>(fix, mask, part, diagpart);
  reduce_kernel<<<(B_ * D_) / 256, 256, 0, stream>>>(part, mask, diagpart, blkout);
  final_kernel<<<1, 128, 0, stream>>>(blkout, out);
}